// Round 11
// baseline (239.465 us; speedup 1.0000x reference)
//
#include <hip/hip_runtime.h>
#include <hip/hip_fp16.h>

// GCN: two-level CSR build + wave-per-node fp16 gather agg + fused MFMA GEMMs.
//   1) k_prep: bucket hist (blocks<256) + X->fp16 (all blocks) + W1t/W2t cvt
//   2) k_bscan: bucket exclusive scan
//   3) k_binscatter: LDS hist -> bulk cursor reservation -> low-contention scatter
//   4) k_sort: per-bucket LDS counting sort -> edge_src (dst-sorted), row_start
//   5) k_agg128h: agg1h[n] = fp16((1/deg) * sum X16[src])  (16 gathers in flight)
//   6) k_mgemm2: m2h = fp16( relu(agg1h@W1+b1) @ W2 )      (fused, barrier-fenced)
//   7) k_agg64h: out[n] = (1/deg) * sum m2h[src] + b2      (16 in flight/wave)
// Requires N <= 2^17. N = 100000 here.

constexpr int CAP = 6144;
constexpr int CHUNK = 8192;

typedef _Float16 f16x8 __attribute__((ext_vector_type(8)));
typedef float f32x4 __attribute__((ext_vector_type(4)));

__global__ __launch_bounds__(256) void k_prep(
    const int* __restrict__ dst, int* __restrict__ bcnt,
    const float* __restrict__ X, __half* __restrict__ X16,
    const float* __restrict__ W1, const float* __restrict__ W2,
    __half* __restrict__ W1t, __half* __restrict__ W2t,
    int E, int NB, long long n4)
{
    __shared__ int sh[1024];
    const int tid = threadIdx.x;
    if (blockIdx.x < 256) {
        for (int i = tid; i < NB; i += 256) sh[i] = 0;
        __syncthreads();
        for (int e = blockIdx.x * 256 + tid; e < E; e += 256 * 256)
            atomicAdd(&sh[dst[e] >> 7], 1);
        __syncthreads();
        for (int i = tid; i < NB; i += 256) {
            const int v = sh[i];
            if (v) atomicAdd(&bcnt[i], v);
        }
    } else if (blockIdx.x < 352) {
        const int t = (blockIdx.x - 256) * 256 + tid;   // < 24576 exactly
        if (t < 128 * 128) {
            const int k = t >> 7, n = t & 127;
            W1t[n * 128 + k] = __float2half(W1[t]);
        } else {
            const int u = t - 128 * 128;
            const int k = u >> 6, n = u & 63;
            W2t[n * 128 + k] = __float2half(W2[u]);
        }
    }
    for (long long i = (long long)blockIdx.x * 256 + tid; i < n4;
         i += (long long)gridDim.x * 256) {
        const float4 v = ((const float4*)X)[i];
        __half2 h0 = __floats2half2_rn(v.x, v.y);
        __half2 h1 = __floats2half2_rn(v.z, v.w);
        uint2 o;
        o.x = *(const unsigned*)&h0;
        o.y = *(const unsigned*)&h1;
        ((uint2*)X16)[i] = o;
    }
}

__global__ __launch_bounds__(1024) void k_bscan(
    const int* __restrict__ bcnt, int* __restrict__ bstart,
    int* __restrict__ bcursor, int NB, int E)
{
    __shared__ int sh[1024];
    const int t = threadIdx.x;
    const int v = (t < NB) ? bcnt[t] : 0;
    sh[t] = v;
    __syncthreads();
    for (int off = 1; off < 1024; off <<= 1) {
        int u = (t >= off) ? sh[t - off] : 0;
        __syncthreads();
        if (t >= off) sh[t] += u;
        __syncthreads();
    }
    if (t < NB) {
        const int ex = sh[t] - v;
        bstart[t] = ex;
        bcursor[t] = ex;
    }
    if (t == 0) bstart[NB] = E;
}

__global__ __launch_bounds__(256) void k_binscatter(
    const int* __restrict__ src, const int* __restrict__ dst,
    int* __restrict__ bcursor, unsigned* __restrict__ pairs, int E, int NB)
{
    __shared__ int hist[1024];
    __shared__ int base[1024];
    const int b0 = blockIdx.x * CHUNK;
    const int cnt = min(CHUNK, E - b0);
    const int tid = threadIdx.x;

    for (int i = tid; i < NB; i += 256) hist[i] = 0;
    __syncthreads();
    for (int i = tid; i < cnt; i += 256)
        atomicAdd(&hist[dst[b0 + i] >> 7], 1);
    __syncthreads();
    for (int i = tid; i < NB; i += 256) {
        const int c = hist[i];
        base[i] = c ? atomicAdd(&bcursor[i], c) : 0;
    }
    __syncthreads();
    int i = tid;
    for (; i + 1792 < cnt; i += 2048) {
        int d[8], s[8], p[8];
#pragma unroll
        for (int q = 0; q < 8; ++q) {
            d[q] = dst[b0 + i + q * 256];
            s[q] = src[b0 + i + q * 256];
        }
#pragma unroll
        for (int q = 0; q < 8; ++q) p[q] = atomicAdd(&base[d[q] >> 7], 1);
#pragma unroll
        for (int q = 0; q < 8; ++q)
            pairs[p[q]] = (unsigned)s[q] | ((unsigned)(d[q] & 127) << 17);
    }
    for (; i < cnt; i += 256) {
        const int d = dst[b0 + i];
        const int p = atomicAdd(&base[d >> 7], 1);
        pairs[p] = (unsigned)src[b0 + i] | ((unsigned)(d & 127) << 17);
    }
}

__global__ __launch_bounds__(256) void k_sort(
    const unsigned* __restrict__ pairs, const int* __restrict__ bstart,
    int* __restrict__ edge_src, int* __restrict__ row_start, int N, int E)
{
    __shared__ unsigned sp[CAP];
    __shared__ int sorted[CAP];
    __shared__ int lcnt[128];
    __shared__ int ls[128];
    const int b = blockIdx.x;
    const int tid = threadIdx.x;
    const int beg = bstart[b], end = bstart[b + 1];
    const int cnt = end - beg;
    const bool fits = (cnt <= CAP);

    if (tid < 128) lcnt[tid] = 0;
    __syncthreads();

    if (fits) {
        for (int i = tid; i < cnt; i += 256) {
            const unsigned p = pairs[beg + i];
            sp[i] = p;
            atomicAdd(&lcnt[p >> 17], 1);
        }
    } else {
        for (int i = tid; i < cnt; i += 256)
            atomicAdd(&lcnt[pairs[beg + i] >> 17], 1);
    }
    __syncthreads();

    if (tid < 128) ls[tid] = lcnt[tid];
    __syncthreads();
    for (int off = 1; off < 128; off <<= 1) {
        int v = 0;
        if (tid < 128 && tid >= off) v = ls[tid - off];
        __syncthreads();
        if (tid < 128 && tid >= off) ls[tid] += v;
        __syncthreads();
    }

    if (tid < 128) {
        const int node = b * 128 + tid;
        if (node <= N) row_start[node] = beg + ls[tid] - lcnt[tid];
    }
    if (b == 0 && tid == 0) row_start[N] = E;
    __syncthreads();

    if (tid < 128) ls[tid] -= lcnt[tid];
    __syncthreads();

    if (fits) {
        for (int i = tid; i < cnt; i += 256) {
            const unsigned p = sp[i];
            const int pos = atomicAdd(&ls[p >> 17], 1);
            sorted[pos] = (int)(p & 0x1FFFFu);
        }
        __syncthreads();
        for (int i = tid; i < cnt; i += 256) edge_src[beg + i] = sorted[i];
    } else {
        for (int i = tid; i < cnt; i += 256) {
            const unsigned p = pairs[beg + i];
            const int pos = atomicAdd(&ls[p >> 17], 1);
            edge_src[beg + pos] = (int)(p & 0x1FFFFu);
        }
    }
}

// Layer-1 agg: wave per node, fp16 gather (128 ch), f32 acc, fp16 out w/ 1/deg.
// 16 row-gathers in flight per wave; 32-bit gather offsets.
__global__ __launch_bounds__(256) void k_agg128h(
    const __half* __restrict__ M, const int* __restrict__ edge_src,
    const int* __restrict__ row_start, __half* __restrict__ outp, int N)
{
    const int w = (blockIdx.x * 256 + threadIdx.x) >> 6;
    if (w >= N) return;
    const unsigned lane = threadIdx.x & 63;
    const int beg = row_start[w];
    const int end = row_start[w + 1];
    const float inv = 1.0f / fmaxf((float)(end - beg), 1.0f);
    const __half2* M2 = (const __half2*)M;

    float ax = 0.f, ay = 0.f, bx = 0.f, by = 0.f;
    float cx = 0.f, cy = 0.f, dx = 0.f, dy = 0.f;
    int j = beg;
    for (; j + 15 < end; j += 16) {
        unsigned o[16];
#pragma unroll
        for (int q = 0; q < 16; ++q)
            o[q] = ((unsigned)edge_src[j + q] << 6) | lane;
        float2 v[16];
#pragma unroll
        for (int q = 0; q < 16; ++q) v[q] = __half22float2(M2[o[q]]);
        ax += v[0].x + v[4].x + v[8].x + v[12].x;
        ay += v[0].y + v[4].y + v[8].y + v[12].y;
        bx += v[1].x + v[5].x + v[9].x + v[13].x;
        by += v[1].y + v[5].y + v[9].y + v[13].y;
        cx += v[2].x + v[6].x + v[10].x + v[14].x;
        cy += v[2].y + v[6].y + v[10].y + v[14].y;
        dx += v[3].x + v[7].x + v[11].x + v[15].x;
        dy += v[3].y + v[7].y + v[11].y + v[15].y;
    }
    for (; j + 3 < end; j += 4) {
        const unsigned o0 = ((unsigned)edge_src[j + 0] << 6) | lane;
        const unsigned o1 = ((unsigned)edge_src[j + 1] << 6) | lane;
        const unsigned o2 = ((unsigned)edge_src[j + 2] << 6) | lane;
        const unsigned o3 = ((unsigned)edge_src[j + 3] << 6) | lane;
        const float2 v0 = __half22float2(M2[o0]);
        const float2 v1 = __half22float2(M2[o1]);
        const float2 v2 = __half22float2(M2[o2]);
        const float2 v3 = __half22float2(M2[o3]);
        ax += v0.x + v2.x; ay += v0.y + v2.y;
        bx += v1.x + v3.x; by += v1.y + v3.y;
    }
    for (; j < end; ++j) {
        const float2 v = __half22float2(M2[((unsigned)edge_src[j] << 6) | lane]);
        ax += v.x; ay += v.y;
    }
    const float sx = (ax + bx) + (cx + dx);
    const float sy = (ay + by) + (cy + dy);
    ((__half2*)(outp + (size_t)w * 128))[lane] = __floats2half2_rn(sx * inv, sy * inv);
}

// Layer-2 agg: wave per node, half-wave per edge, 8 in flight per half-wave
// (16/wave), f32 acc, combine via shfl_xor(32), epi = *inv + b2.
__global__ __launch_bounds__(256) void k_agg64h(
    const __half* __restrict__ M, const int* __restrict__ edge_src,
    const int* __restrict__ row_start, const float* __restrict__ bias,
    float* __restrict__ outp, int N)
{
    const int w = (blockIdx.x * 256 + threadIdx.x) >> 6;
    if (w >= N) return;
    const int lane = threadIdx.x & 63;
    const int half = lane >> 5;
    const unsigned l = lane & 31;
    const int beg = row_start[w];
    const int end = row_start[w + 1];
    const float inv = 1.0f / fmaxf((float)(end - beg), 1.0f);
    const __half2* M2 = (const __half2*)M;

    float ax = 0.f, ay = 0.f, bx = 0.f, by = 0.f;
    float cx = 0.f, cy = 0.f, dx = 0.f, dy = 0.f;
    int j = beg + half;
    for (; j + 14 < end; j += 16) {
        unsigned o[8];
#pragma unroll
        for (int q = 0; q < 8; ++q)
            o[q] = ((unsigned)edge_src[j + 2 * q] << 5) | l;
        float2 v[8];
#pragma unroll
        for (int q = 0; q < 8; ++q) v[q] = __half22float2(M2[o[q]]);
        ax += v[0].x + v[4].x; ay += v[0].y + v[4].y;
        bx += v[1].x + v[5].x; by += v[1].y + v[5].y;
        cx += v[2].x + v[6].x; cy += v[2].y + v[6].y;
        dx += v[3].x + v[7].x; dy += v[3].y + v[7].y;
    }
    for (; j < end; j += 2) {
        const float2 v = __half22float2(M2[((unsigned)edge_src[j] << 5) | l]);
        ax += v.x; ay += v.y;
    }
    ax = (ax + bx) + (cx + dx);
    ay = (ay + by) + (cy + dy);
    ax += __shfl_xor(ax, 32);
    ay += __shfl_xor(ay, 32);
    if (half == 0) {
        const float2 b = ((const float2*)bias)[l];
        float2 o;
        o.x = fmaf(ax, inv, b.x);
        o.y = fmaf(ay, inv, b.y);
        ((float2*)(outp + (size_t)w * 64))[l] = o;
    }
}

// Fused MFMA GEMM: m2h = fp16( relu(A@W1 + b1) @ W2 ), 64 rows/block, 4 waves.
// Every LDS write->read phase crossing is fenced with __syncthreads so the
// compiler cannot reorder may-aliasing DS ops (TBAA across __half/f16x8/uint4).
__global__ __launch_bounds__(256) void k_mgemm2(
    const __half* __restrict__ A, const __half* __restrict__ W1t,
    const float* __restrict__ b1, const __half* __restrict__ W2t,
    __half* __restrict__ C, int N)
{
    __shared__ __align__(16) char lds[16384];
    const int tid = threadIdx.x;
    const int row0 = blockIdx.x * 64;

    // phase 1: stage A tile (64 x 128 fp16), XOR-swizzled rows
    for (int i = tid; i < 1024; i += 256) {
        const int r = i >> 4, ch = i & 15;
        const int row = row0 + r;
        uint4 v = make_uint4(0, 0, 0, 0);
        if (row < N) v = *(const uint4*)(A + (size_t)row * 128 + ch * 8);
        *(uint4*)(lds + r * 256 + ((ch * 16) ^ ((r & 7) << 4))) = v;
    }
    __syncthreads();

    const int w = tid >> 6, l = tid & 63;
    const int lr = l & 15, lk = l >> 4;
    const int arow = w * 16 + lr;

    // phase 2: GEMM1
    f32x4 acc1[8] = {};
#pragma unroll
    for (int kb = 0; kb < 4; ++kb) {
        const f16x8 a = *(const f16x8*)(lds + arow * 256 +
                                        ((kb * 64 + lk * 16) ^ ((arow & 7) << 4)));
#pragma unroll
        for (int nt = 0; nt < 8; ++nt) {
            const f16x8 b = *(const f16x8*)(W1t + (nt * 16 + lr) * 128 + kb * 32 + lk * 8);
            acc1[nt] = __builtin_amdgcn_mfma_f32_16x16x32_f16(a, b, acc1[nt], 0, 0, 0);
        }
    }
    __syncthreads();   // A-tile reads done (cross-wave staging)

    // phase 3: h tile (16 x 128 fp16, bias+relu) -> wave-private swizzled LDS
    char* hw = lds + w * 4096;
#pragma unroll
    for (int nt = 0; nt < 8; ++nt) {
        const int col = nt * 16 + lr;
        const float bv = b1[col];
#pragma unroll
        for (int i = 0; i < 4; ++i) {
            const int r = lk * 4 + i;
            const float v = fmaxf(acc1[nt][i] + bv, 0.f);
            *(__half*)(hw + r * 256 + ((col * 2) ^ ((r & 7) << 4))) = __float2half(v);
        }
    }
    __syncthreads();   // fence: h writes ordered before a2 reads

    // phase 4: GEMM2 from LDS h
    f32x4 acc2[4] = {};
#pragma unroll
    for (int kb = 0; kb < 4; ++kb) {
        const f16x8 a2 = *(const f16x8*)(hw + lr * 256 +
                                         ((kb * 64 + lk * 16) ^ ((lr & 7) << 4)));
#pragma unroll
        for (int nt = 0; nt < 4; ++nt) {
            const f16x8 b = *(const f16x8*)(W2t + (nt * 16 + lr) * 128 + kb * 32 + lk * 8);
            acc2[nt] = __builtin_amdgcn_mfma_f32_16x16x32_f16(a2, b, acc2[nt], 0, 0, 0);
        }
    }
    __syncthreads();   // fence: a2 reads done before m2 overwrites h region

    // phase 5: m2 tile (16 x 64 fp16) bounce in the same wave region
#pragma unroll
    for (int nt = 0; nt < 4; ++nt) {
        const int col = nt * 16 + lr;
#pragma unroll
        for (int i = 0; i < 4; ++i) {
            const int r = lk * 4 + i;
            *(__half*)(hw + r * 128 + ((col * 2) ^ ((r & 7) << 4))) = __float2half(acc2[nt][i]);
        }
    }
    __syncthreads();   // fence: m2 writes ordered before copy-out reads

    // phase 6: coalesced copy-out
    const int rbase = row0 + w * 16;
    for (int i = l; i < 128; i += 64) {
        const int r = i >> 3, c = i & 7;
        const int row = rbase + r;
        if (row < N)
            *(uint4*)(C + (size_t)row * 64 + c * 8) =
                *(const uint4*)(hw + r * 128 + ((c * 16) ^ ((r & 7) << 4)));
    }
}

extern "C" void kernel_launch(void* const* d_in, const int* in_sizes, int n_in,
                              void* d_out, int out_size, void* d_ws, size_t ws_size,
                              hipStream_t stream)
{
    const float* X  = (const float*)d_in[0];
    const int*  src = (const int*)d_in[1];
    const int*  dst = (const int*)d_in[2];
    const float* W1 = (const float*)d_in[3];
    const float* b1 = (const float*)d_in[4];
    const float* W2 = (const float*)d_in[5];
    const float* b2 = (const float*)d_in[6];
    float* out = (float*)d_out;

    const int N = in_sizes[0] / 128;
    const int E = in_sizes[1];
    const int NB = (N + 127) / 128;

    __half* X16   = (__half*)d_ws;                       // N*128 f16
    __half* agg1h = X16 + (size_t)N * 128;               // N*128 f16
    __half* scr   = agg1h + (size_t)N * 128;             // N*128 f16 region: pairs
    __half* m2h   = X16;                                 // alias X16 (dead after agg1)
    unsigned* pairs = (unsigned*)scr;                    // E u32 (fits in scr)
    int* edge_src  = (int*)(scr + (size_t)N * 128);      // E
    int* row_start = edge_src + E;                       // N+1
    int* bcnt      = row_start + N + 1;                  // NB
    int* bstart    = bcnt + NB;                          // NB+1
    int* bcursor   = bstart + NB + 1;                    // NB
    __half* W1t    = (__half*)(bcursor + NB);            // 128*128 f16
    __half* W2t    = W1t + 128 * 128;                    // 64*128 f16

    hipMemsetAsync(bcnt, 0, (size_t)NB * sizeof(int), stream);

    // --- prep (hist + X->fp16 + W transposes) & CSR build ---
    k_prep<<<2048, 256, 0, stream>>>(dst, bcnt, X, X16, W1, W2, W1t, W2t,
                                     E, NB, (long long)N * 32);
    k_bscan<<<1, 1024, 0, stream>>>(bcnt, bstart, bcursor, NB, E);
    k_binscatter<<<(E + CHUNK - 1) / CHUNK, 256, 0, stream>>>(src, dst, bcursor, pairs, E, NB);
    k_sort<<<NB, 256, 0, stream>>>(pairs, bstart, edge_src, row_start, N, E);

    // --- layer 1 agg, fused GEMM1+GEMM2, layer 2 agg ---
    k_agg128h<<<(N + 3) / 4, 256, 0, stream>>>(X16, edge_src, row_start, agg1h, N);
    k_mgemm2<<<(N + 63) / 64, 256, 0, stream>>>(agg1h, W1t, b1, W2t, m2h, N);
    k_agg64h<<<(N + 3) / 4, 256, 0, stream>>>(m2h, edge_src, row_start, b2, out, N);
}

// Round 12
// 218.368 us; speedup vs baseline: 1.0966x; 1.0966x over previous
//
#include <hip/hip_runtime.h>
#include <hip/hip_fp16.h>

// GCN: two-level CSR build + lane-group gather aggregation + fused MFMA GEMMs.
//   1) k_prep: bucket hist (blocks<256) + X->fp16 (all blocks) + W1t/W2t cvt
//   2) k_bscan: bucket exclusive scan
//   3) k_binscatter: LDS hist -> bulk cursor reservation -> low-contention scatter
//   4) k_sort: per-bucket LDS counting sort -> edge_src (dst-sorted), row_start
//   5) k_agg1: agg1h[n] = fp16((1/deg) * sum X16[src])   (16 lanes/node, 4 nodes/wave)
//   6) k_mgemm2: m2h = fp16( relu(agg1h@W1+b1) @ W2 )    (fused, barrier-fenced)
//   7) k_agg2: out[n] = (1/deg) * sum m2h[src] + b2      (8 lanes/node, 8 nodes/wave)
// Requires N <= 2^17. N = 100000 here.

constexpr int CAP = 6144;
constexpr int CHUNK = 8192;

typedef _Float16 f16x8 __attribute__((ext_vector_type(8)));
typedef float f32x4 __attribute__((ext_vector_type(4)));

__global__ __launch_bounds__(256) void k_prep(
    const int* __restrict__ dst, int* __restrict__ bcnt,
    const float* __restrict__ X, __half* __restrict__ X16,
    const float* __restrict__ W1, const float* __restrict__ W2,
    __half* __restrict__ W1t, __half* __restrict__ W2t,
    int E, int NB, long long n4)
{
    __shared__ int sh[1024];
    const int tid = threadIdx.x;
    if (blockIdx.x < 256) {
        for (int i = tid; i < NB; i += 256) sh[i] = 0;
        __syncthreads();
        for (int e = blockIdx.x * 256 + tid; e < E; e += 256 * 256)
            atomicAdd(&sh[dst[e] >> 7], 1);
        __syncthreads();
        for (int i = tid; i < NB; i += 256) {
            const int v = sh[i];
            if (v) atomicAdd(&bcnt[i], v);
        }
    } else if (blockIdx.x < 352) {
        const int t = (blockIdx.x - 256) * 256 + tid;   // < 24576 exactly
        if (t < 128 * 128) {
            const int k = t >> 7, n = t & 127;
            W1t[n * 128 + k] = __float2half(W1[t]);
        } else {
            const int u = t - 128 * 128;
            const int k = u >> 6, n = u & 63;
            W2t[n * 128 + k] = __float2half(W2[u]);
        }
    }
    for (long long i = (long long)blockIdx.x * 256 + tid; i < n4;
         i += (long long)gridDim.x * 256) {
        const float4 v = ((const float4*)X)[i];
        __half2 h0 = __floats2half2_rn(v.x, v.y);
        __half2 h1 = __floats2half2_rn(v.z, v.w);
        uint2 o;
        o.x = *(const unsigned*)&h0;
        o.y = *(const unsigned*)&h1;
        ((uint2*)X16)[i] = o;
    }
}

__global__ __launch_bounds__(1024) void k_bscan(
    const int* __restrict__ bcnt, int* __restrict__ bstart,
    int* __restrict__ bcursor, int NB, int E)
{
    __shared__ int sh[1024];
    const int t = threadIdx.x;
    const int v = (t < NB) ? bcnt[t] : 0;
    sh[t] = v;
    __syncthreads();
    for (int off = 1; off < 1024; off <<= 1) {
        int u = (t >= off) ? sh[t - off] : 0;
        __syncthreads();
        if (t >= off) sh[t] += u;
        __syncthreads();
    }
    if (t < NB) {
        const int ex = sh[t] - v;
        bstart[t] = ex;
        bcursor[t] = ex;
    }
    if (t == 0) bstart[NB] = E;
}

__global__ __launch_bounds__(256) void k_binscatter(
    const int* __restrict__ src, const int* __restrict__ dst,
    int* __restrict__ bcursor, unsigned* __restrict__ pairs, int E, int NB)
{
    __shared__ int hist[1024];
    __shared__ int base[1024];
    const int b0 = blockIdx.x * CHUNK;
    const int cnt = min(CHUNK, E - b0);
    const int tid = threadIdx.x;

    for (int i = tid; i < NB; i += 256) hist[i] = 0;
    __syncthreads();
    for (int i = tid; i < cnt; i += 256)
        atomicAdd(&hist[dst[b0 + i] >> 7], 1);
    __syncthreads();
    for (int i = tid; i < NB; i += 256) {
        const int c = hist[i];
        base[i] = c ? atomicAdd(&bcursor[i], c) : 0;
    }
    __syncthreads();
    int i = tid;
    for (; i + 768 < cnt; i += 1024) {
        const int d0 = dst[b0 + i], s0 = src[b0 + i];
        const int d1 = dst[b0 + i + 256], s1 = src[b0 + i + 256];
        const int d2 = dst[b0 + i + 512], s2 = src[b0 + i + 512];
        const int d3 = dst[b0 + i + 768], s3 = src[b0 + i + 768];
        const int p0 = atomicAdd(&base[d0 >> 7], 1);
        const int p1 = atomicAdd(&base[d1 >> 7], 1);
        const int p2 = atomicAdd(&base[d2 >> 7], 1);
        const int p3 = atomicAdd(&base[d3 >> 7], 1);
        pairs[p0] = (unsigned)s0 | ((unsigned)(d0 & 127) << 17);
        pairs[p1] = (unsigned)s1 | ((unsigned)(d1 & 127) << 17);
        pairs[p2] = (unsigned)s2 | ((unsigned)(d2 & 127) << 17);
        pairs[p3] = (unsigned)s3 | ((unsigned)(d3 & 127) << 17);
    }
    for (; i < cnt; i += 256) {
        const int d = dst[b0 + i];
        const int p = atomicAdd(&base[d >> 7], 1);
        pairs[p] = (unsigned)src[b0 + i] | ((unsigned)(d & 127) << 17);
    }
}

__global__ __launch_bounds__(256) void k_sort(
    const unsigned* __restrict__ pairs, const int* __restrict__ bstart,
    int* __restrict__ edge_src, int* __restrict__ row_start, int N, int E)
{
    __shared__ unsigned sp[CAP];
    __shared__ int sorted[CAP];
    __shared__ int lcnt[128];
    __shared__ int ls[128];
    const int b = blockIdx.x;
    const int tid = threadIdx.x;
    const int beg = bstart[b], end = bstart[b + 1];
    const int cnt = end - beg;
    const bool fits = (cnt <= CAP);

    if (tid < 128) lcnt[tid] = 0;
    __syncthreads();

    if (fits) {
        for (int i = tid; i < cnt; i += 256) {
            const unsigned p = pairs[beg + i];
            sp[i] = p;
            atomicAdd(&lcnt[p >> 17], 1);
        }
    } else {
        for (int i = tid; i < cnt; i += 256)
            atomicAdd(&lcnt[pairs[beg + i] >> 17], 1);
    }
    __syncthreads();

    if (tid < 128) ls[tid] = lcnt[tid];
    __syncthreads();
    for (int off = 1; off < 128; off <<= 1) {
        int v = 0;
        if (tid < 128 && tid >= off) v = ls[tid - off];
        __syncthreads();
        if (tid < 128 && tid >= off) ls[tid] += v;
        __syncthreads();
    }

    if (tid < 128) {
        const int node = b * 128 + tid;
        if (node <= N) row_start[node] = beg + ls[tid] - lcnt[tid];
    }
    if (b == 0 && tid == 0) row_start[N] = E;
    __syncthreads();

    if (tid < 128) ls[tid] -= lcnt[tid];
    __syncthreads();

    if (fits) {
        for (int i = tid; i < cnt; i += 256) {
            const unsigned p = sp[i];
            const int pos = atomicAdd(&ls[p >> 17], 1);
            sorted[pos] = (int)(p & 0x1FFFFu);
        }
        __syncthreads();
        for (int i = tid; i < cnt; i += 256) edge_src[beg + i] = sorted[i];
    } else {
        for (int i = tid; i < cnt; i += 256) {
            const unsigned p = pairs[beg + i];
            const int pos = atomicAdd(&ls[p >> 17], 1);
            edge_src[beg + pos] = (int)(p & 0x1FFFFu);
        }
    }
}

// Layer-1 agg: 16 lanes per node (4 nodes/wave). Each lane owns 8 channels
// (one uint4 = 8 fp16). Per wave-load: 4 independent 256-B rows in flight.
__global__ __launch_bounds__(256) void k_agg1(
    const __half* __restrict__ M, const int* __restrict__ edge_src,
    const int* __restrict__ row_start, __half* __restrict__ outp, int N)
{
    const int node = (blockIdx.x * 256 + threadIdx.x) >> 4;
    if (node >= N) return;
    const unsigned li = threadIdx.x & 15;
    const int beg = row_start[node];
    const int end = row_start[node + 1];
    const float inv = 1.0f / fmaxf((float)(end - beg), 1.0f);
    const uint4* M4 = (const uint4*)M;   // 16 uint4 per row

    float acc[8] = {};
    int j = beg;
    for (; j + 7 < end; j += 8) {
        unsigned o[8];
#pragma unroll
        for (int q = 0; q < 8; ++q)
            o[q] = ((unsigned)edge_src[j + q] << 4) | li;
        uint4 v[8];
#pragma unroll
        for (int q = 0; q < 8; ++q) v[q] = M4[o[q]];
#pragma unroll
        for (int q = 0; q < 8; ++q) {
            const __half2* h = (const __half2*)&v[q];
#pragma unroll
            for (int p = 0; p < 4; ++p) {
                const float2 f = __half22float2(h[p]);
                acc[2 * p] += f.x;
                acc[2 * p + 1] += f.y;
            }
        }
    }
    for (; j < end; ++j) {
        const uint4 v = M4[((unsigned)edge_src[j] << 4) | li];
        const __half2* h = (const __half2*)&v;
#pragma unroll
        for (int p = 0; p < 4; ++p) {
            const float2 f = __half22float2(h[p]);
            acc[2 * p] += f.x;
            acc[2 * p + 1] += f.y;
        }
    }
    __half2 r[4];
#pragma unroll
    for (int p = 0; p < 4; ++p)
        r[p] = __floats2half2_rn(acc[2 * p] * inv, acc[2 * p + 1] * inv);
    ((uint4*)(outp + (size_t)node * 128))[li] = *(const uint4*)r;
}

// Layer-2 agg: 8 lanes per node (8 nodes/wave). Each lane owns 8 channels.
// f32 out with 1/deg and bias fused.
__global__ __launch_bounds__(256) void k_agg2(
    const __half* __restrict__ M, const int* __restrict__ edge_src,
    const int* __restrict__ row_start, const float* __restrict__ bias,
    float* __restrict__ outp, int N)
{
    const int node = (blockIdx.x * 256 + threadIdx.x) >> 3;
    if (node >= N) return;
    const unsigned li = threadIdx.x & 7;
    const int beg = row_start[node];
    const int end = row_start[node + 1];
    const float inv = 1.0f / fmaxf((float)(end - beg), 1.0f);
    const uint4* M4 = (const uint4*)M;   // 8 uint4 per row

    float acc[8] = {};
    int j = beg;
    for (; j + 7 < end; j += 8) {
        unsigned o[8];
#pragma unroll
        for (int q = 0; q < 8; ++q)
            o[q] = ((unsigned)edge_src[j + q] << 3) | li;
        uint4 v[8];
#pragma unroll
        for (int q = 0; q < 8; ++q) v[q] = M4[o[q]];
#pragma unroll
        for (int q = 0; q < 8; ++q) {
            const __half2* h = (const __half2*)&v[q];
#pragma unroll
            for (int p = 0; p < 4; ++p) {
                const float2 f = __half22float2(h[p]);
                acc[2 * p] += f.x;
                acc[2 * p + 1] += f.y;
            }
        }
    }
    for (; j < end; ++j) {
        const uint4 v = M4[((unsigned)edge_src[j] << 3) | li];
        const __half2* h = (const __half2*)&v;
#pragma unroll
        for (int p = 0; p < 4; ++p) {
            const float2 f = __half22float2(h[p]);
            acc[2 * p] += f.x;
            acc[2 * p + 1] += f.y;
        }
    }
    const float4 b0 = ((const float4*)bias)[li * 2];
    const float4 b1 = ((const float4*)bias)[li * 2 + 1];
    float4 o0, o1;
    o0.x = fmaf(acc[0], inv, b0.x);
    o0.y = fmaf(acc[1], inv, b0.y);
    o0.z = fmaf(acc[2], inv, b0.z);
    o0.w = fmaf(acc[3], inv, b0.w);
    o1.x = fmaf(acc[4], inv, b1.x);
    o1.y = fmaf(acc[5], inv, b1.y);
    o1.z = fmaf(acc[6], inv, b1.z);
    o1.w = fmaf(acc[7], inv, b1.w);
    float4* op = (float4*)(outp + (size_t)node * 64);
    op[li * 2] = o0;
    op[li * 2 + 1] = o1;
}

// Fused MFMA GEMM: m2h = fp16( relu(A@W1 + b1) @ W2 ), 64 rows/block, 4 waves.
// Every LDS write->read phase crossing is fenced with __syncthreads so the
// compiler cannot reorder may-aliasing DS ops (TBAA across __half/f16x8/uint4).
__global__ __launch_bounds__(256) void k_mgemm2(
    const __half* __restrict__ A, const __half* __restrict__ W1t,
    const float* __restrict__ b1, const __half* __restrict__ W2t,
    __half* __restrict__ C, int N)
{
    __shared__ __align__(16) char lds[16384];
    const int tid = threadIdx.x;
    const int row0 = blockIdx.x * 64;

    // phase 1: stage A tile (64 x 128 fp16), XOR-swizzled rows
    for (int i = tid; i < 1024; i += 256) {
        const int r = i >> 4, ch = i & 15;
        const int row = row0 + r;
        uint4 v = make_uint4(0, 0, 0, 0);
        if (row < N) v = *(const uint4*)(A + (size_t)row * 128 + ch * 8);
        *(uint4*)(lds + r * 256 + ((ch * 16) ^ ((r & 7) << 4))) = v;
    }
    __syncthreads();

    const int w = tid >> 6, l = tid & 63;
    const int lr = l & 15, lk = l >> 4;
    const int arow = w * 16 + lr;

    // phase 2: GEMM1
    f32x4 acc1[8] = {};
#pragma unroll
    for (int kb = 0; kb < 4; ++kb) {
        const f16x8 a = *(const f16x8*)(lds + arow * 256 +
                                        ((kb * 64 + lk * 16) ^ ((arow & 7) << 4)));
#pragma unroll
        for (int nt = 0; nt < 8; ++nt) {
            const f16x8 b = *(const f16x8*)(W1t + (nt * 16 + lr) * 128 + kb * 32 + lk * 8);
            acc1[nt] = __builtin_amdgcn_mfma_f32_16x16x32_f16(a, b, acc1[nt], 0, 0, 0);
        }
    }
    __syncthreads();   // A-tile reads done (cross-wave staging)

    // phase 3: h tile (16 x 128 fp16, bias+relu) -> wave-private swizzled LDS
    char* hw = lds + w * 4096;
#pragma unroll
    for (int nt = 0; nt < 8; ++nt) {
        const int col = nt * 16 + lr;
        const float bv = b1[col];
#pragma unroll
        for (int i = 0; i < 4; ++i) {
            const int r = lk * 4 + i;
            const float v = fmaxf(acc1[nt][i] + bv, 0.f);
            *(__half*)(hw + r * 256 + ((col * 2) ^ ((r & 7) << 4))) = __float2half(v);
        }
    }
    __syncthreads();   // fence: h writes ordered before a2 reads

    // phase 4: GEMM2 from LDS h
    f32x4 acc2[4] = {};
#pragma unroll
    for (int kb = 0; kb < 4; ++kb) {
        const f16x8 a2 = *(const f16x8*)(hw + lr * 256 +
                                         ((kb * 64 + lk * 16) ^ ((lr & 7) << 4)));
#pragma unroll
        for (int nt = 0; nt < 4; ++nt) {
            const f16x8 b = *(const f16x8*)(W2t + (nt * 16 + lr) * 128 + kb * 32 + lk * 8);
            acc2[nt] = __builtin_amdgcn_mfma_f32_16x16x32_f16(a2, b, acc2[nt], 0, 0, 0);
        }
    }
    __syncthreads();   // fence: a2 reads done before m2 overwrites h region

    // phase 5: m2 tile (16 x 64 fp16) bounce in the same wave region
#pragma unroll
    for (int nt = 0; nt < 4; ++nt) {
        const int col = nt * 16 + lr;
#pragma unroll
        for (int i = 0; i < 4; ++i) {
            const int r = lk * 4 + i;
            *(__half*)(hw + r * 128 + ((col * 2) ^ ((r & 7) << 4))) = __float2half(acc2[nt][i]);
        }
    }
    __syncthreads();   // fence: m2 writes ordered before copy-out reads

    // phase 6: coalesced copy-out
    const int rbase = row0 + w * 16;
    for (int i = l; i < 128; i += 64) {
        const int r = i >> 3, c = i & 7;
        const int row = rbase + r;
        if (row < N)
            *(uint4*)(C + (size_t)row * 64 + c * 8) =
                *(const uint4*)(hw + r * 128 + ((c * 16) ^ ((r & 7) << 4)));
    }
}

extern "C" void kernel_launch(void* const* d_in, const int* in_sizes, int n_in,
                              void* d_out, int out_size, void* d_ws, size_t ws_size,
                              hipStream_t stream)
{
    const float* X  = (const float*)d_in[0];
    const int*  src = (const int*)d_in[1];
    const int*  dst = (const int*)d_in[2];
    const float* W1 = (const float*)d_in[3];
    const float* b1 = (const float*)d_in[4];
    const float* W2 = (const float*)d_in[5];
    const float* b2 = (const float*)d_in[6];
    float* out = (float*)d_out;

    const int N = in_sizes[0] / 128;
    const int E = in_sizes[1];
    const int NB = (N + 127) / 128;

    __half* X16   = (__half*)d_ws;                       // N*128 f16
    __half* agg1h = X16 + (size_t)N * 128;               // N*128 f16
    __half* scr   = agg1h + (size_t)N * 128;             // N*128 f16 region: pairs
    __half* m2h   = X16;                                 // alias X16 (dead after agg1)
    unsigned* pairs = (unsigned*)scr;                    // E u32 (fits in scr)
    int* edge_src  = (int*)(scr + (size_t)N * 128);      // E
    int* row_start = edge_src + E;                       // N+1
    int* bcnt      = row_start + N + 1;                  // NB
    int* bstart    = bcnt + NB;                          // NB+1
    int* bcursor   = bstart + NB + 1;                    // NB
    __half* W1t    = (__half*)(bcursor + NB);            // 128*128 f16
    __half* W2t    = W1t + 128 * 128;                    // 64*128 f16

    hipMemsetAsync(bcnt, 0, (size_t)NB * sizeof(int), stream);

    // --- prep (hist + X->fp16 + W transposes) & CSR build ---
    k_prep<<<2048, 256, 0, stream>>>(dst, bcnt, X, X16, W1, W2, W1t, W2t,
                                     E, NB, (long long)N * 32);
    k_bscan<<<1, 1024, 0, stream>>>(bcnt, bstart, bcursor, NB, E);
    k_binscatter<<<(E + CHUNK - 1) / CHUNK, 256, 0, stream>>>(src, dst, bcursor, pairs, E, NB);
    k_sort<<<NB, 256, 0, stream>>>(pairs, bstart, edge_src, row_start, N, E);

    // --- layer 1 agg, fused GEMM1+GEMM2, layer 2 agg ---
    k_agg1<<<(N * 16 + 255) / 256, 256, 0, stream>>>(X16, edge_src, row_start, agg1h, N);
    k_mgemm2<<<(N + 63) / 64, 256, 0, stream>>>(agg1h, W1t, b1, W2t, m2h, N);
    k_agg2<<<(N * 8 + 255) / 256, 256, 0, stream>>>(m2h, edge_src, row_start, b2, out, N);
}

// Round 13
// 200.159 us; speedup vs baseline: 1.1964x; 1.0910x over previous
//
#include <hip/hip_runtime.h>
#include <hip/hip_fp16.h>

// GCN: atomic-free two-level CSR build + lane-group gather agg + fused MFMA GEMMs.
//   1) k_prep: per-chunk bucket hist -> counts[chunk][bucket] (no atomics)
//              + X->fp16 convert + W1t/W2t transpose-convert
//   2) k_colscan: per-bucket exclusive prefix over chunks (in-place) + totals
//   3) k_bscan: bucket exclusive scan of totals -> bstart
//   4) k_scatter2: LDS cursors from bstart+cbase; rank via LDS atomics only
//   5) k_sort: per-bucket LDS counting sort -> edge_src (dst-sorted), row_start
//   6) k_agg1: agg1h[n] = fp16((1/deg) * sum X16[src])  (16 lanes/node)
//   7) k_mgemm2: m2h = fp16( relu(agg1h@W1+b1) @ W2 )   (fused, barrier-fenced)
//   8) k_agg2: out[n] = (1/deg) * sum m2h[src] + b2     (8 lanes/node)
// Requires N <= 2^17. N = 100000 here.

constexpr int CAP = 6144;
constexpr int CHUNK = 4096;

typedef _Float16 f16x8 __attribute__((ext_vector_type(8)));
typedef float f32x4 __attribute__((ext_vector_type(4)));

// blocks < NC: hist of chunk -> counts[c][b] (coalesced store, no atomics)
// blocks NC..NC+95: W transposes; all blocks: X->fp16 grid-stride convert.
__global__ __launch_bounds__(256) void k_prep(
    const int* __restrict__ dst, int* __restrict__ counts,
    const float* __restrict__ X, __half* __restrict__ X16,
    const float* __restrict__ W1, const float* __restrict__ W2,
    __half* __restrict__ W1t, __half* __restrict__ W2t,
    int E, int NB, int NC, long long n4)
{
    __shared__ int sh[1024];
    const int tid = threadIdx.x;
    if (blockIdx.x < NC) {
        const int c = blockIdx.x;
        const int b0 = c * CHUNK;
        const int cnt = min(CHUNK, E - b0);
        for (int i = tid; i < NB; i += 256) sh[i] = 0;
        __syncthreads();
        for (int i = tid; i < cnt; i += 256)
            atomicAdd(&sh[dst[b0 + i] >> 7], 1);
        __syncthreads();
        for (int i = tid; i < NB; i += 256) counts[(size_t)c * NB + i] = sh[i];
    } else if (blockIdx.x < NC + 96) {
        const int t = (blockIdx.x - NC) * 256 + tid;   // < 24576 exactly
        if (t < 128 * 128) {
            const int k = t >> 7, n = t & 127;
            W1t[n * 128 + k] = __float2half(W1[t]);
        } else {
            const int u = t - 128 * 128;
            const int k = u >> 6, n = u & 63;
            W2t[n * 128 + k] = __float2half(W2[u]);
        }
    }
    for (long long i = (long long)blockIdx.x * 256 + tid; i < n4;
         i += (long long)gridDim.x * 256) {
        const float4 v = ((const float4*)X)[i];
        __half2 h0 = __floats2half2_rn(v.x, v.y);
        __half2 h1 = __floats2half2_rn(v.z, v.w);
        uint2 o;
        o.x = *(const unsigned*)&h0;
        o.y = *(const unsigned*)&h1;
        ((uint2*)X16)[i] = o;
    }
}

// One block per bucket: exclusive prefix of counts[*][b] over chunks (in-place),
// totals -> btot[b].
__global__ __launch_bounds__(256) void k_colscan(
    int* __restrict__ counts, int* __restrict__ btot, int NB, int NC)
{
    __shared__ int sh[256];
    const int b = blockIdx.x;
    const int tid = threadIdx.x;
    int carry = 0;
    for (int t0 = 0; t0 < NC; t0 += 256) {
        const int idx = t0 + tid;
        const int v = (idx < NC) ? counts[(size_t)idx * NB + b] : 0;
        sh[tid] = v;
        __syncthreads();
        for (int off = 1; off < 256; off <<= 1) {
            int u = (tid >= off) ? sh[tid - off] : 0;
            __syncthreads();
            if (tid >= off) sh[tid] += u;
            __syncthreads();
        }
        const int incl = sh[tid];
        const int tile_total = sh[255];
        if (idx < NC) counts[(size_t)idx * NB + b] = incl - v + carry;
        carry += tile_total;
        __syncthreads();   // sh reused next tile
    }
    if (tid == 0) btot[b] = carry;
}

__global__ __launch_bounds__(1024) void k_bscan(
    const int* __restrict__ btot, int* __restrict__ bstart, int NB, int E)
{
    __shared__ int sh[1024];
    const int t = threadIdx.x;
    const int v = (t < NB) ? btot[t] : 0;
    sh[t] = v;
    __syncthreads();
    for (int off = 1; off < 1024; off <<= 1) {
        int u = (t >= off) ? sh[t - off] : 0;
        __syncthreads();
        if (t >= off) sh[t] += u;
        __syncthreads();
    }
    if (t < NB) bstart[t] = sh[t] - v;
    if (t == 0) bstart[NB] = E;
}

// One block per chunk: cursors = bstart[b] + cbase[c][b]; LDS-atomic rank;
// scattered store into block-private bucket windows. Zero global atomics.
__global__ __launch_bounds__(256) void k_scatter2(
    const int* __restrict__ src, const int* __restrict__ dst,
    const int* __restrict__ cbase, const int* __restrict__ bstart,
    unsigned* __restrict__ pairs, int E, int NB)
{
    __shared__ int cur[1024];
    const int c = blockIdx.x;
    const int b0 = c * CHUNK;
    const int cnt = min(CHUNK, E - b0);
    const int tid = threadIdx.x;

    for (int i = tid; i < NB; i += 256)
        cur[i] = bstart[i] + cbase[(size_t)c * NB + i];
    __syncthreads();

    int i = tid;
    for (; i + 768 < cnt; i += 1024) {
        const int d0 = dst[b0 + i], s0 = src[b0 + i];
        const int d1 = dst[b0 + i + 256], s1 = src[b0 + i + 256];
        const int d2 = dst[b0 + i + 512], s2 = src[b0 + i + 512];
        const int d3 = dst[b0 + i + 768], s3 = src[b0 + i + 768];
        const int p0 = atomicAdd(&cur[d0 >> 7], 1);
        const int p1 = atomicAdd(&cur[d1 >> 7], 1);
        const int p2 = atomicAdd(&cur[d2 >> 7], 1);
        const int p3 = atomicAdd(&cur[d3 >> 7], 1);
        pairs[p0] = (unsigned)s0 | ((unsigned)(d0 & 127) << 17);
        pairs[p1] = (unsigned)s1 | ((unsigned)(d1 & 127) << 17);
        pairs[p2] = (unsigned)s2 | ((unsigned)(d2 & 127) << 17);
        pairs[p3] = (unsigned)s3 | ((unsigned)(d3 & 127) << 17);
    }
    for (; i < cnt; i += 256) {
        const int d = dst[b0 + i];
        const int p = atomicAdd(&cur[d >> 7], 1);
        pairs[p] = (unsigned)src[b0 + i] | ((unsigned)(d & 127) << 17);
    }
}

__global__ __launch_bounds__(256) void k_sort(
    const unsigned* __restrict__ pairs, const int* __restrict__ bstart,
    int* __restrict__ edge_src, int* __restrict__ row_start, int N, int E)
{
    __shared__ unsigned sp[CAP];
    __shared__ int sorted[CAP];
    __shared__ int lcnt[128];
    __shared__ int ls[128];
    const int b = blockIdx.x;
    const int tid = threadIdx.x;
    const int beg = bstart[b], end = bstart[b + 1];
    const int cnt = end - beg;
    const bool fits = (cnt <= CAP);

    if (tid < 128) lcnt[tid] = 0;
    __syncthreads();

    if (fits) {
        for (int i = tid; i < cnt; i += 256) {
            const unsigned p = pairs[beg + i];
            sp[i] = p;
            atomicAdd(&lcnt[p >> 17], 1);
        }
    } else {
        for (int i = tid; i < cnt; i += 256)
            atomicAdd(&lcnt[pairs[beg + i] >> 17], 1);
    }
    __syncthreads();

    if (tid < 128) ls[tid] = lcnt[tid];
    __syncthreads();
    for (int off = 1; off < 128; off <<= 1) {
        int v = 0;
        if (tid < 128 && tid >= off) v = ls[tid - off];
        __syncthreads();
        if (tid < 128 && tid >= off) ls[tid] += v;
        __syncthreads();
    }

    if (tid < 128) {
        const int node = b * 128 + tid;
        if (node <= N) row_start[node] = beg + ls[tid] - lcnt[tid];
    }
    if (b == 0 && tid == 0) row_start[N] = E;
    __syncthreads();

    if (tid < 128) ls[tid] -= lcnt[tid];
    __syncthreads();

    if (fits) {
        for (int i = tid; i < cnt; i += 256) {
            const unsigned p = sp[i];
            const int pos = atomicAdd(&ls[p >> 17], 1);
            sorted[pos] = (int)(p & 0x1FFFFu);
        }
        __syncthreads();
        for (int i = tid; i < cnt; i += 256) edge_src[beg + i] = sorted[i];
    } else {
        for (int i = tid; i < cnt; i += 256) {
            const unsigned p = pairs[beg + i];
            const int pos = atomicAdd(&ls[p >> 17], 1);
            edge_src[beg + pos] = (int)(p & 0x1FFFFu);
        }
    }
}

// Layer-1 agg: 16 lanes per node (4 nodes/wave). Each lane owns 8 channels
// (one uint4 = 8 fp16). Per wave-load: 4 independent 256-B rows in flight.
__global__ __launch_bounds__(256) void k_agg1(
    const __half* __restrict__ M, const int* __restrict__ edge_src,
    const int* __restrict__ row_start, __half* __restrict__ outp, int N)
{
    const int node = (blockIdx.x * 256 + threadIdx.x) >> 4;
    if (node >= N) return;
    const unsigned li = threadIdx.x & 15;
    const int beg = row_start[node];
    const int end = row_start[node + 1];
    const float inv = 1.0f / fmaxf((float)(end - beg), 1.0f);
    const uint4* M4 = (const uint4*)M;   // 16 uint4 per row

    float acc[8] = {};
    int j = beg;
    for (; j + 7 < end; j += 8) {
        unsigned o[8];
#pragma unroll
        for (int q = 0; q < 8; ++q)
            o[q] = ((unsigned)edge_src[j + q] << 4) | li;
        uint4 v[8];
#pragma unroll
        for (int q = 0; q < 8; ++q) v[q] = M4[o[q]];
#pragma unroll
        for (int q = 0; q < 8; ++q) {
            const __half2* h = (const __half2*)&v[q];
#pragma unroll
            for (int p = 0; p < 4; ++p) {
                const float2 f = __half22float2(h[p]);
                acc[2 * p] += f.x;
                acc[2 * p + 1] += f.y;
            }
        }
    }
    for (; j < end; ++j) {
        const uint4 v = M4[((unsigned)edge_src[j] << 4) | li];
        const __half2* h = (const __half2*)&v;
#pragma unroll
        for (int p = 0; p < 4; ++p) {
            const float2 f = __half22float2(h[p]);
            acc[2 * p] += f.x;
            acc[2 * p + 1] += f.y;
        }
    }
    __half2 r[4];
#pragma unroll
    for (int p = 0; p < 4; ++p)
        r[p] = __floats2half2_rn(acc[2 * p] * inv, acc[2 * p + 1] * inv);
    ((uint4*)(outp + (size_t)node * 128))[li] = *(const uint4*)r;
}

// Layer-2 agg: 8 lanes per node (8 nodes/wave). Each lane owns 8 channels.
// f32 out with 1/deg and bias fused.
__global__ __launch_bounds__(256) void k_agg2(
    const __half* __restrict__ M, const int* __restrict__ edge_src,
    const int* __restrict__ row_start, const float* __restrict__ bias,
    float* __restrict__ outp, int N)
{
    const int node = (blockIdx.x * 256 + threadIdx.x) >> 3;
    if (node >= N) return;
    const unsigned li = threadIdx.x & 7;
    const int beg = row_start[node];
    const int end = row_start[node + 1];
    const float inv = 1.0f / fmaxf((float)(end - beg), 1.0f);
    const uint4* M4 = (const uint4*)M;   // 8 uint4 per row

    float acc[8] = {};
    int j = beg;
    for (; j + 7 < end; j += 8) {
        unsigned o[8];
#pragma unroll
        for (int q = 0; q < 8; ++q)
            o[q] = ((unsigned)edge_src[j + q] << 3) | li;
        uint4 v[8];
#pragma unroll
        for (int q = 0; q < 8; ++q) v[q] = M4[o[q]];
#pragma unroll
        for (int q = 0; q < 8; ++q) {
            const __half2* h = (const __half2*)&v[q];
#pragma unroll
            for (int p = 0; p < 4; ++p) {
                const float2 f = __half22float2(h[p]);
                acc[2 * p] += f.x;
                acc[2 * p + 1] += f.y;
            }
        }
    }
    for (; j < end; ++j) {
        const uint4 v = M4[((unsigned)edge_src[j] << 3) | li];
        const __half2* h = (const __half2*)&v;
#pragma unroll
        for (int p = 0; p < 4; ++p) {
            const float2 f = __half22float2(h[p]);
            acc[2 * p] += f.x;
            acc[2 * p + 1] += f.y;
        }
    }
    const float4 b0 = ((const float4*)bias)[li * 2];
    const float4 b1 = ((const float4*)bias)[li * 2 + 1];
    float4 o0, o1;
    o0.x = fmaf(acc[0], inv, b0.x);
    o0.y = fmaf(acc[1], inv, b0.y);
    o0.z = fmaf(acc[2], inv, b0.z);
    o0.w = fmaf(acc[3], inv, b0.w);
    o1.x = fmaf(acc[4], inv, b1.x);
    o1.y = fmaf(acc[5], inv, b1.y);
    o1.z = fmaf(acc[6], inv, b1.z);
    o1.w = fmaf(acc[7], inv, b1.w);
    float4* op = (float4*)(outp + (size_t)node * 64);
    op[li * 2] = o0;
    op[li * 2 + 1] = o1;
}

// Fused MFMA GEMM: m2h = fp16( relu(A@W1 + b1) @ W2 ), 64 rows/block, 4 waves.
// Every LDS write->read phase crossing is fenced with __syncthreads.
__global__ __launch_bounds__(256) void k_mgemm2(
    const __half* __restrict__ A, const __half* __restrict__ W1t,
    const float* __restrict__ b1, const __half* __restrict__ W2t,
    __half* __restrict__ C, int N)
{
    __shared__ __align__(16) char lds[16384];
    const int tid = threadIdx.x;
    const int row0 = blockIdx.x * 64;

    // phase 1: stage A tile (64 x 128 fp16), XOR-swizzled rows
    for (int i = tid; i < 1024; i += 256) {
        const int r = i >> 4, ch = i & 15;
        const int row = row0 + r;
        uint4 v = make_uint4(0, 0, 0, 0);
        if (row < N) v = *(const uint4*)(A + (size_t)row * 128 + ch * 8);
        *(uint4*)(lds + r * 256 + ((ch * 16) ^ ((r & 7) << 4))) = v;
    }
    __syncthreads();

    const int w = tid >> 6, l = tid & 63;
    const int lr = l & 15, lk = l >> 4;
    const int arow = w * 16 + lr;

    // phase 2: GEMM1
    f32x4 acc1[8] = {};
#pragma unroll
    for (int kb = 0; kb < 4; ++kb) {
        const f16x8 a = *(const f16x8*)(lds + arow * 256 +
                                        ((kb * 64 + lk * 16) ^ ((arow & 7) << 4)));
#pragma unroll
        for (int nt = 0; nt < 8; ++nt) {
            const f16x8 b = *(const f16x8*)(W1t + (nt * 16 + lr) * 128 + kb * 32 + lk * 8);
            acc1[nt] = __builtin_amdgcn_mfma_f32_16x16x32_f16(a, b, acc1[nt], 0, 0, 0);
        }
    }
    __syncthreads();   // A-tile reads done (cross-wave staging)

    // phase 3: h tile (16 x 128 fp16, bias+relu) -> wave-private swizzled LDS
    char* hw = lds + w * 4096;
#pragma unroll
    for (int nt = 0; nt < 8; ++nt) {
        const int col = nt * 16 + lr;
        const float bv = b1[col];
#pragma unroll
        for (int i = 0; i < 4; ++i) {
            const int r = lk * 4 + i;
            const float v = fmaxf(acc1[nt][i] + bv, 0.f);
            *(__half*)(hw + r * 256 + ((col * 2) ^ ((r & 7) << 4))) = __float2half(v);
        }
    }
    __syncthreads();   // fence: h writes ordered before a2 reads

    // phase 4: GEMM2 from LDS h
    f32x4 acc2[4] = {};
#pragma unroll
    for (int kb = 0; kb < 4; ++kb) {
        const f16x8 a2 = *(const f16x8*)(hw + lr * 256 +
                                         ((kb * 64 + lk * 16) ^ ((lr & 7) << 4)));
#pragma unroll
        for (int nt = 0; nt < 4; ++nt) {
            const f16x8 b = *(const f16x8*)(W2t + (nt * 16 + lr) * 128 + kb * 32 + lk * 8);
            acc2[nt] = __builtin_amdgcn_mfma_f32_16x16x32_f16(a2, b, acc2[nt], 0, 0, 0);
        }
    }
    __syncthreads();   // fence: a2 reads done before m2 overwrites h region

    // phase 5: m2 tile (16 x 64 fp16) bounce in the same wave region
#pragma unroll
    for (int nt = 0; nt < 4; ++nt) {
        const int col = nt * 16 + lr;
#pragma unroll
        for (int i = 0; i < 4; ++i) {
            const int r = lk * 4 + i;
            *(__half*)(hw + r * 128 + ((col * 2) ^ ((r & 7) << 4))) = __float2half(acc2[nt][i]);
        }
    }
    __syncthreads();   // fence: m2 writes ordered before copy-out reads

    // phase 6: coalesced copy-out
    const int rbase = row0 + w * 16;
    for (int i = l; i < 128; i += 64) {
        const int r = i >> 3, c = i & 7;
        const int row = rbase + r;
        if (row < N)
            *(uint4*)(C + (size_t)row * 64 + c * 8) =
                *(const uint4*)(hw + r * 128 + ((c * 16) ^ ((r & 7) << 4)));
    }
}

extern "C" void kernel_launch(void* const* d_in, const int* in_sizes, int n_in,
                              void* d_out, int out_size, void* d_ws, size_t ws_size,
                              hipStream_t stream)
{
    const float* X  = (const float*)d_in[0];
    const int*  src = (const int*)d_in[1];
    const int*  dst = (const int*)d_in[2];
    const float* W1 = (const float*)d_in[3];
    const float* b1 = (const float*)d_in[4];
    const float* W2 = (const float*)d_in[5];
    const float* b2 = (const float*)d_in[6];
    float* out = (float*)d_out;

    const int N = in_sizes[0] / 128;
    const int E = in_sizes[1];
    const int NB = (N + 127) / 128;
    const int NC = (E + CHUNK - 1) / CHUNK;

    __half* X16   = (__half*)d_ws;                       // N*128 f16
    __half* agg1h = X16 + (size_t)N * 128;               // N*128 f16
    __half* scr   = agg1h + (size_t)N * 128;             // N*128 f16 region
    __half* m2h   = X16;                                 // alias X16 (dead after agg1)
    unsigned* pairs = (unsigned*)scr;                    // E u32 (fits in scr)
    int* edge_src  = (int*)(scr + (size_t)N * 128);      // E
    int* row_start = edge_src + E;                       // N+1
    int* bstart    = row_start + N + 1;                  // NB+1
    int* btot      = bstart + NB + 1;                    // NB
    int* counts    = btot + NB;                          // NC*NB (cbase after scan)
    __half* W1t    = (__half*)(counts + (size_t)NC * NB); // 128*128 f16
    __half* W2t    = W1t + 128 * 128;                    // 64*128 f16

    // --- atomic-free CSR build (+ fused X->fp16, W transposes) ---
    k_prep<<<2048, 256, 0, stream>>>(dst, counts, X, X16, W1, W2, W1t, W2t,
                                     E, NB, NC, (long long)N * 32);
    k_colscan<<<NB, 256, 0, stream>>>(counts, btot, NB, NC);
    k_bscan<<<1, 1024, 0, stream>>>(btot, bstart, NB, E);
    k_scatter2<<<NC, 256, 0, stream>>>(src, dst, counts, bstart, pairs, E, NB);
    k_sort<<<NB, 256, 0, stream>>>(pairs, bstart, edge_src, row_start, N, E);

    // --- layer 1 agg, fused GEMM1+GEMM2, layer 2 agg ---
    k_agg1<<<(N * 16 + 255) / 256, 256, 0, stream>>>(X16, edge_src, row_start, agg1h, N);
    k_mgemm2<<<(N + 63) / 64, 256, 0, stream>>>(agg1h, W1t, b1, W2t, m2h, N);
    k_agg2<<<(N * 8 + 255) / 256, 256, 0, stream>>>(m2h, edge_src, row_start, b2, out, N);
}

// Round 14
// 192.052 us; speedup vs baseline: 1.2469x; 1.0422x over previous
//
#include <hip/hip_runtime.h>
#include <hip/hip_fp16.h>

// GCN: atomic-free two-level CSR build + lane-group gather agg + fused MFMA GEMMs.
//   1) k_prep: per-chunk bucket hist -> counts[chunk][bucket] (no atomics)
//              + X->fp16 convert + W1t/W2t transpose-convert
//   2) k_colscan: per-bucket exclusive prefix over chunks (in-place) + totals
//   3) k_bscan: bucket exclusive scan of totals -> bstart
//   4) k_scatter2: LDS cursors from bstart+cbase; rank via LDS atomics only
//   5) k_sort: per-bucket LDS counting sort -> edge_src (dst-sorted), row_start
//   6) k_agg1: agg1h[n] = fp16((1/deg) * sum X16[src])  (16 lanes/node)
//   7) k_mgemm2: m2h = fp16( relu(agg1h@W1+b1) @ W2 )   (fused, barrier-fenced)
//   8) k_agg2: out[n] = (1/deg) * sum m2h[src] + b2     (8 lanes/node, 16 deep)
// Requires N <= 2^17. N = 100000 here.

constexpr int CAP = 3072;      // max edges/bucket on LDS sort fast path (avg ~2048, max ~2300)
constexpr int CHUNK = 8192;    // edges per scatter chunk (longer per-bucket runs)

typedef _Float16 f16x8 __attribute__((ext_vector_type(8)));
typedef float f32x4 __attribute__((ext_vector_type(4)));

// blocks < NC: hist of chunk -> counts[c][b] (coalesced store, no atomics)
// blocks NC..NC+95: W transposes; all blocks: X->fp16 grid-stride convert.
__global__ __launch_bounds__(256) void k_prep(
    const int* __restrict__ dst, int* __restrict__ counts,
    const float* __restrict__ X, __half* __restrict__ X16,
    const float* __restrict__ W1, const float* __restrict__ W2,
    __half* __restrict__ W1t, __half* __restrict__ W2t,
    int E, int NB, int NC, long long n4)
{
    __shared__ int sh[1024];
    const int tid = threadIdx.x;
    if (blockIdx.x < NC) {
        const int c = blockIdx.x;
        const int b0 = c * CHUNK;
        const int cnt = min(CHUNK, E - b0);
        for (int i = tid; i < NB; i += 256) sh[i] = 0;
        __syncthreads();
        for (int i = tid; i < cnt; i += 256)
            atomicAdd(&sh[dst[b0 + i] >> 7], 1);
        __syncthreads();
        for (int i = tid; i < NB; i += 256) counts[(size_t)c * NB + i] = sh[i];
    } else if (blockIdx.x < NC + 96) {
        const int t = (blockIdx.x - NC) * 256 + tid;   // < 24576 exactly
        if (t < 128 * 128) {
            const int k = t >> 7, n = t & 127;
            W1t[n * 128 + k] = __float2half(W1[t]);
        } else {
            const int u = t - 128 * 128;
            const int k = u >> 6, n = u & 63;
            W2t[n * 128 + k] = __float2half(W2[u]);
        }
    }
    for (long long i = (long long)blockIdx.x * 256 + tid; i < n4;
         i += (long long)gridDim.x * 256) {
        const float4 v = ((const float4*)X)[i];
        __half2 h0 = __floats2half2_rn(v.x, v.y);
        __half2 h1 = __floats2half2_rn(v.z, v.w);
        uint2 o;
        o.x = *(const unsigned*)&h0;
        o.y = *(const unsigned*)&h1;
        ((uint2*)X16)[i] = o;
    }
}

// One block per bucket: exclusive prefix of counts[*][b] over chunks (in-place),
// totals -> btot[b].
__global__ __launch_bounds__(256) void k_colscan(
    int* __restrict__ counts, int* __restrict__ btot, int NB, int NC)
{
    __shared__ int sh[256];
    const int b = blockIdx.x;
    const int tid = threadIdx.x;
    int carry = 0;
    for (int t0 = 0; t0 < NC; t0 += 256) {
        const int idx = t0 + tid;
        const int v = (idx < NC) ? counts[(size_t)idx * NB + b] : 0;
        sh[tid] = v;
        __syncthreads();
        for (int off = 1; off < 256; off <<= 1) {
            int u = (tid >= off) ? sh[tid - off] : 0;
            __syncthreads();
            if (tid >= off) sh[tid] += u;
            __syncthreads();
        }
        const int incl = sh[tid];
        const int tile_total = sh[255];
        if (idx < NC) counts[(size_t)idx * NB + b] = incl - v + carry;
        carry += tile_total;
        __syncthreads();   // sh reused next tile
    }
    if (tid == 0) btot[b] = carry;
}

__global__ __launch_bounds__(1024) void k_bscan(
    const int* __restrict__ btot, int* __restrict__ bstart, int NB, int E)
{
    __shared__ int sh[1024];
    const int t = threadIdx.x;
    const int v = (t < NB) ? btot[t] : 0;
    sh[t] = v;
    __syncthreads();
    for (int off = 1; off < 1024; off <<= 1) {
        int u = (t >= off) ? sh[t - off] : 0;
        __syncthreads();
        if (t >= off) sh[t] += u;
        __syncthreads();
    }
    if (t < NB) bstart[t] = sh[t] - v;
    if (t == 0) bstart[NB] = E;
}

// One block per chunk: cursors = bstart[b] + cbase[c][b]; LDS-atomic rank;
// scattered store into block-private bucket windows. Zero global atomics.
__global__ __launch_bounds__(256) void k_scatter2(
    const int* __restrict__ src, const int* __restrict__ dst,
    const int* __restrict__ cbase, const int* __restrict__ bstart,
    unsigned* __restrict__ pairs, int E, int NB)
{
    __shared__ int cur[1024];
    const int c = blockIdx.x;
    const int b0 = c * CHUNK;
    const int cnt = min(CHUNK, E - b0);
    const int tid = threadIdx.x;

    for (int i = tid; i < NB; i += 256)
        cur[i] = bstart[i] + cbase[(size_t)c * NB + i];
    __syncthreads();

    int i = tid;
    for (; i + 768 < cnt; i += 1024) {
        const int d0 = dst[b0 + i], s0 = src[b0 + i];
        const int d1 = dst[b0 + i + 256], s1 = src[b0 + i + 256];
        const int d2 = dst[b0 + i + 512], s2 = src[b0 + i + 512];
        const int d3 = dst[b0 + i + 768], s3 = src[b0 + i + 768];
        const int p0 = atomicAdd(&cur[d0 >> 7], 1);
        const int p1 = atomicAdd(&cur[d1 >> 7], 1);
        const int p2 = atomicAdd(&cur[d2 >> 7], 1);
        const int p3 = atomicAdd(&cur[d3 >> 7], 1);
        pairs[p0] = (unsigned)s0 | ((unsigned)(d0 & 127) << 17);
        pairs[p1] = (unsigned)s1 | ((unsigned)(d1 & 127) << 17);
        pairs[p2] = (unsigned)s2 | ((unsigned)(d2 & 127) << 17);
        pairs[p3] = (unsigned)s3 | ((unsigned)(d3 & 127) << 17);
    }
    for (; i < cnt; i += 256) {
        const int d = dst[b0 + i];
        const int p = atomicAdd(&cur[d >> 7], 1);
        pairs[p] = (unsigned)src[b0 + i] | ((unsigned)(d & 127) << 17);
    }
}

__global__ __launch_bounds__(256) void k_sort(
    const unsigned* __restrict__ pairs, const int* __restrict__ bstart,
    int* __restrict__ edge_src, int* __restrict__ row_start, int N, int E)
{
    __shared__ unsigned sp[CAP];
    __shared__ int sorted[CAP];
    __shared__ int lcnt[128];
    __shared__ int ls[128];
    const int b = blockIdx.x;
    const int tid = threadIdx.x;
    const int beg = bstart[b], end = bstart[b + 1];
    const int cnt = end - beg;
    const bool fits = (cnt <= CAP);

    if (tid < 128) lcnt[tid] = 0;
    __syncthreads();

    if (fits) {
        for (int i = tid; i < cnt; i += 256) {
            const unsigned p = pairs[beg + i];
            sp[i] = p;
            atomicAdd(&lcnt[p >> 17], 1);
        }
    } else {
        for (int i = tid; i < cnt; i += 256)
            atomicAdd(&lcnt[pairs[beg + i] >> 17], 1);
    }
    __syncthreads();

    if (tid < 128) ls[tid] = lcnt[tid];
    __syncthreads();
    for (int off = 1; off < 128; off <<= 1) {
        int v = 0;
        if (tid < 128 && tid >= off) v = ls[tid - off];
        __syncthreads();
        if (tid < 128 && tid >= off) ls[tid] += v;
        __syncthreads();
    }

    if (tid < 128) {
        const int node = b * 128 + tid;
        if (node <= N) row_start[node] = beg + ls[tid] - lcnt[tid];
    }
    if (b == 0 && tid == 0) row_start[N] = E;
    __syncthreads();

    if (tid < 128) ls[tid] -= lcnt[tid];
    __syncthreads();

    if (fits) {
        for (int i = tid; i < cnt; i += 256) {
            const unsigned p = sp[i];
            const int pos = atomicAdd(&ls[p >> 17], 1);
            sorted[pos] = (int)(p & 0x1FFFFu);
        }
        __syncthreads();
        for (int i = tid; i < cnt; i += 256) edge_src[beg + i] = sorted[i];
    } else {
        for (int i = tid; i < cnt; i += 256) {
            const unsigned p = pairs[beg + i];
            const int pos = atomicAdd(&ls[p >> 17], 1);
            edge_src[beg + pos] = (int)(p & 0x1FFFFu);
        }
    }
}

// Layer-1 agg: 16 lanes per node (4 nodes/wave). Each lane owns 8 channels
// (one uint4 = 8 fp16). Per wave-load: 4 independent 256-B rows in flight.
__global__ __launch_bounds__(256) void k_agg1(
    const __half* __restrict__ M, const int* __restrict__ edge_src,
    const int* __restrict__ row_start, __half* __restrict__ outp, int N)
{
    const int node = (blockIdx.x * 256 + threadIdx.x) >> 4;
    if (node >= N) return;
    const unsigned li = threadIdx.x & 15;
    const int beg = row_start[node];
    const int end = row_start[node + 1];
    const float inv = 1.0f / fmaxf((float)(end - beg), 1.0f);
    const uint4* M4 = (const uint4*)M;   // 16 uint4 per row

    float acc[8] = {};
    int j = beg;
    for (; j + 7 < end; j += 8) {
        unsigned o[8];
#pragma unroll
        for (int q = 0; q < 8; ++q)
            o[q] = ((unsigned)edge_src[j + q] << 4) | li;
        uint4 v[8];
#pragma unroll
        for (int q = 0; q < 8; ++q) v[q] = M4[o[q]];
#pragma unroll
        for (int q = 0; q < 8; ++q) {
            const __half2* h = (const __half2*)&v[q];
#pragma unroll
            for (int p = 0; p < 4; ++p) {
                const float2 f = __half22float2(h[p]);
                acc[2 * p] += f.x;
                acc[2 * p + 1] += f.y;
            }
        }
    }
    for (; j < end; ++j) {
        const uint4 v = M4[((unsigned)edge_src[j] << 4) | li];
        const __half2* h = (const __half2*)&v;
#pragma unroll
        for (int p = 0; p < 4; ++p) {
            const float2 f = __half22float2(h[p]);
            acc[2 * p] += f.x;
            acc[2 * p + 1] += f.y;
        }
    }
    __half2 r[4];
#pragma unroll
    for (int p = 0; p < 4; ++p)
        r[p] = __floats2half2_rn(acc[2 * p] * inv, acc[2 * p + 1] * inv);
    ((uint4*)(outp + (size_t)node * 128))[li] = *(const uint4*)r;
}

// Layer-2 agg: 8 lanes per node (8 nodes/wave), 16 edges in flight per group.
// f32 out with 1/deg and bias fused.
__global__ __launch_bounds__(256) void k_agg2(
    const __half* __restrict__ M, const int* __restrict__ edge_src,
    const int* __restrict__ row_start, const float* __restrict__ bias,
    float* __restrict__ outp, int N)
{
    const int node = (blockIdx.x * 256 + threadIdx.x) >> 3;
    if (node >= N) return;
    const unsigned li = threadIdx.x & 7;
    const int beg = row_start[node];
    const int end = row_start[node + 1];
    const float inv = 1.0f / fmaxf((float)(end - beg), 1.0f);
    const uint4* M4 = (const uint4*)M;   // 8 uint4 per row

    float acc[8] = {};
    int j = beg;
    for (; j + 15 < end; j += 16) {
        unsigned o[16];
#pragma unroll
        for (int q = 0; q < 16; ++q)
            o[q] = ((unsigned)edge_src[j + q] << 3) | li;
        uint4 v[16];
#pragma unroll
        for (int q = 0; q < 16; ++q) v[q] = M4[o[q]];
#pragma unroll
        for (int q = 0; q < 16; ++q) {
            const __half2* h = (const __half2*)&v[q];
#pragma unroll
            for (int p = 0; p < 4; ++p) {
                const float2 f = __half22float2(h[p]);
                acc[2 * p] += f.x;
                acc[2 * p + 1] += f.y;
            }
        }
    }
    for (; j + 3 < end; j += 4) {
        unsigned o[4];
#pragma unroll
        for (int q = 0; q < 4; ++q)
            o[q] = ((unsigned)edge_src[j + q] << 3) | li;
        uint4 v[4];
#pragma unroll
        for (int q = 0; q < 4; ++q) v[q] = M4[o[q]];
#pragma unroll
        for (int q = 0; q < 4; ++q) {
            const __half2* h = (const __half2*)&v[q];
#pragma unroll
            for (int p = 0; p < 4; ++p) {
                const float2 f = __half22float2(h[p]);
                acc[2 * p] += f.x;
                acc[2 * p + 1] += f.y;
            }
        }
    }
    for (; j < end; ++j) {
        const uint4 v = M4[((unsigned)edge_src[j] << 3) | li];
        const __half2* h = (const __half2*)&v;
#pragma unroll
        for (int p = 0; p < 4; ++p) {
            const float2 f = __half22float2(h[p]);
            acc[2 * p] += f.x;
            acc[2 * p + 1] += f.y;
        }
    }
    const float4 b0 = ((const float4*)bias)[li * 2];
    const float4 b1 = ((const float4*)bias)[li * 2 + 1];
    float4 o0, o1;
    o0.x = fmaf(acc[0], inv, b0.x);
    o0.y = fmaf(acc[1], inv, b0.y);
    o0.z = fmaf(acc[2], inv, b0.z);
    o0.w = fmaf(acc[3], inv, b0.w);
    o1.x = fmaf(acc[4], inv, b1.x);
    o1.y = fmaf(acc[5], inv, b1.y);
    o1.z = fmaf(acc[6], inv, b1.z);
    o1.w = fmaf(acc[7], inv, b1.w);
    float4* op = (float4*)(outp + (size_t)node * 64);
    op[li * 2] = o0;
    op[li * 2 + 1] = o1;
}

// Fused MFMA GEMM: m2h = fp16( relu(A@W1 + b1) @ W2 ), 64 rows/block, 4 waves.
// Every LDS write->read phase crossing is fenced with __syncthreads.
__global__ __launch_bounds__(256) void k_mgemm2(
    const __half* __restrict__ A, const __half* __restrict__ W1t,
    const float* __restrict__ b1, const __half* __restrict__ W2t,
    __half* __restrict__ C, int N)
{
    __shared__ __align__(16) char lds[16384];
    const int tid = threadIdx.x;
    const int row0 = blockIdx.x * 64;

    // phase 1: stage A tile (64 x 128 fp16), XOR-swizzled rows
    for (int i = tid; i < 1024; i += 256) {
        const int r = i >> 4, ch = i & 15;
        const int row = row0 + r;
        uint4 v = make_uint4(0, 0, 0, 0);
        if (row < N) v = *(const uint4*)(A + (size_t)row * 128 + ch * 8);
        *(uint4*)(lds + r * 256 + ((ch * 16) ^ ((r & 7) << 4))) = v;
    }
    __syncthreads();

    const int w = tid >> 6, l = tid & 63;
    const int lr = l & 15, lk = l >> 4;
    const int arow = w * 16 + lr;

    // phase 2: GEMM1
    f32x4 acc1[8] = {};
#pragma unroll
    for (int kb = 0; kb < 4; ++kb) {
        const f16x8 a = *(const f16x8*)(lds + arow * 256 +
                                        ((kb * 64 + lk * 16) ^ ((arow & 7) << 4)));
#pragma unroll
        for (int nt = 0; nt < 8; ++nt) {
            const f16x8 b = *(const f16x8*)(W1t + (nt * 16 + lr) * 128 + kb * 32 + lk * 8);
            acc1[nt] = __builtin_amdgcn_mfma_f32_16x16x32_f16(a, b, acc1[nt], 0, 0, 0);
        }
    }
    __syncthreads();   // A-tile reads done (cross-wave staging)

    // phase 3: h tile (16 x 128 fp16, bias+relu) -> wave-private swizzled LDS
    char* hw = lds + w * 4096;
#pragma unroll
    for (int nt = 0; nt < 8; ++nt) {
        const int col = nt * 16 + lr;
        const float bv = b1[col];
#pragma unroll
        for (int i = 0; i < 4; ++i) {
            const int r = lk * 4 + i;
            const float v = fmaxf(acc1[nt][i] + bv, 0.f);
            *(__half*)(hw + r * 256 + ((col * 2) ^ ((r & 7) << 4))) = __float2half(v);
        }
    }
    __syncthreads();   // fence: h writes ordered before a2 reads

    // phase 4: GEMM2 from LDS h
    f32x4 acc2[4] = {};
#pragma unroll
    for (int kb = 0; kb < 4; ++kb) {
        const f16x8 a2 = *(const f16x8*)(hw + lr * 256 +
                                         ((kb * 64 + lk * 16) ^ ((lr & 7) << 4)));
#pragma unroll
        for (int nt = 0; nt < 4; ++nt) {
            const f16x8 b = *(const f16x8*)(W2t + (nt * 16 + lr) * 128 + kb * 32 + lk * 8);
            acc2[nt] = __builtin_amdgcn_mfma_f32_16x16x32_f16(a2, b, acc2[nt], 0, 0, 0);
        }
    }
    __syncthreads();   // fence: a2 reads done before m2 overwrites h region

    // phase 5: m2 tile (16 x 64 fp16) bounce in the same wave region
#pragma unroll
    for (int nt = 0; nt < 4; ++nt) {
        const int col = nt * 16 + lr;
#pragma unroll
        for (int i = 0; i < 4; ++i) {
            const int r = lk * 4 + i;
            *(__half*)(hw + r * 128 + ((col * 2) ^ ((r & 7) << 4))) = __float2half(acc2[nt][i]);
        }
    }
    __syncthreads();   // fence: m2 writes ordered before copy-out reads

    // phase 6: coalesced copy-out
    const int rbase = row0 + w * 16;
    for (int i = l; i < 128; i += 64) {
        const int r = i >> 3, c = i & 7;
        const int row = rbase + r;
        if (row < N)
            *(uint4*)(C + (size_t)row * 64 + c * 8) =
                *(const uint4*)(hw + r * 128 + ((c * 16) ^ ((r & 7) << 4)));
    }
}

extern "C" void kernel_launch(void* const* d_in, const int* in_sizes, int n_in,
                              void* d_out, int out_size, void* d_ws, size_t ws_size,
                              hipStream_t stream)
{
    const float* X  = (const float*)d_in[0];
    const int*  src = (const int*)d_in[1];
    const int*  dst = (const int*)d_in[2];
    const float* W1 = (const float*)d_in[3];
    const float* b1 = (const float*)d_in[4];
    const float* W2 = (const float*)d_in[5];
    const float* b2 = (const float*)d_in[6];
    float* out = (float*)d_out;

    const int N = in_sizes[0] / 128;
    const int E = in_sizes[1];
    const int NB = (N + 127) / 128;
    const int NC = (E + CHUNK - 1) / CHUNK;

    __half* X16   = (__half*)d_ws;                       // N*128 f16
    __half* agg1h = X16 + (size_t)N * 128;               // N*128 f16
    __half* scr   = agg1h + (size_t)N * 128;             // N*128 f16 region
    __half* m2h   = X16;                                 // alias X16 (dead after agg1)
    unsigned* pairs = (unsigned*)scr;                    // E u32 (fits in scr)
    int* edge_src  = (int*)(scr + (size_t)N * 128);      // E
    int* row_start = edge_src + E;                       // N+1
    int* bstart    = row_start + N + 1;                  // NB+1
    int* btot      = bstart + NB + 1;                    // NB
    int* counts    = btot + NB;                          // NC*NB (cbase after scan)
    __half* W1t    = (__half*)(counts + (size_t)NC * NB); // 128*128 f16
    __half* W2t    = W1t + 128 * 128;                    // 64*128 f16

    // --- atomic-free CSR build (+ fused X->fp16, W transposes) ---
    k_prep<<<2048, 256, 0, stream>>>(dst, counts, X, X16, W1, W2, W1t, W2t,
                                     E, NB, NC, (long long)N * 32);
    k_colscan<<<NB, 256, 0, stream>>>(counts, btot, NB, NC);
    k_bscan<<<1, 1024, 0, stream>>>(btot, bstart, NB, E);
    k_scatter2<<<NC, 256, 0, stream>>>(src, dst, counts, bstart, pairs, E, NB);
    k_sort<<<NB, 256, 0, stream>>>(pairs, bstart, edge_src, row_start, N, E);

    // --- layer 1 agg, fused GEMM1+GEMM2, layer 2 agg ---
    k_agg1<<<(N * 16 + 255) / 256, 256, 0, stream>>>(X16, edge_src, row_start, agg1h, N);
    k_mgemm2<<<(N + 63) / 64, 256, 0, stream>>>(agg1h, W1t, b1, W2t, m2h, N);
    k_agg2<<<(N * 8 + 255) / 256, 256, 0, stream>>>(m2h, edge_src, row_start, b2, out, N);
}